// Round 7
// baseline (560.478 us; speedup 1.0000x reference)
//
#include <hip/hip_runtime.h>
#include <math.h>

typedef _Float16 f16;
typedef f16 f16x2 __attribute__((ext_vector_type(2)));
typedef f16 f16x8 __attribute__((ext_vector_type(8)));
typedef f16 f16x4 __attribute__((ext_vector_type(4)));
typedef float f32x16 __attribute__((ext_vector_type(16)));

// ws layout (f16 units):
//  mid W (w1,w2,w3) per-wave frags, single f16:
//    flat = (((l*2+fg)*8+ks)*2+ft)*512 + (32*g+ln)*8 + i
//  W0 frags at 49152 (2048 f16): ((fg*2+ft)*2+g)*256 + ln*8 + i (k<16, pad 0)
//  packed bias (f32) at f16-offset 53248: 512 floats
//  w4 f16 pairs at 54272: [o][128]: idx o*128+2j+p = w4[4j+2p+o]
#define WS_W0 49152
#define WS_BIAS 53248
#define WS_W4 54272

__global__ void zero_f32(float* __restrict__ p, int n) {
    int i = blockIdx.x * blockDim.x + threadIdx.x;
    if (i < n) p[i] = 0.0f;
}

__global__ void prep_weights(const float* __restrict__ w1, const float* __restrict__ w2,
                             const float* __restrict__ w3, const float* __restrict__ w0,
                             const float* __restrict__ b0, const float* __restrict__ b1,
                             const float* __restrict__ b2, const float* __restrict__ b3,
                             const float* __restrict__ w4, f16* __restrict__ ws) {
    int t = blockIdx.x * 256 + threadIdx.x;
    if (t < 49152) {
        int l = t >> 14;
        int r = t & 16383;
        int k = r >> 7, f = r & 127;
        const float* w = (l == 0) ? w1 : (l == 1) ? w2 : w3;
        float v = w[k * 128 + f];
        int fg = f >> 6, ft = (f >> 5) & 1, ln = f & 31;
        int ks = k >> 4, g = (k >> 3) & 1, i = k & 7;
        ws[(((l * 2 + fg) * 8 + ks) * 2 + ft) * 512 + (32 * g + ln) * 8 + i] = (f16)v;
    } else if (t < 51200) {
        int r = t - 49152;
        int k = r >> 7, f = r & 127;   // k 0..15
        float v = (k < 9) ? w0[k * 128 + f] : 0.0f;
        int fg = f >> 6, ft = (f >> 5) & 1, ln = f & 31;
        int g = (k >> 3) & 1, i = k & 7;
        ws[WS_W0 + ((fg * 2 + ft) * 2 + g) * 256 + ln * 8 + i] = (f16)v;
    } else if (t < 51712) {
        int b = t - 51200;             // 0..511
        int l = b >> 7, r = b & 127;
        int fg = r >> 6, ft = (r >> 5) & 1, g = (r >> 4) & 1, j = (r >> 2) & 3, m = r & 3;
        const float* bl = (l == 0) ? b0 : (l == 1) ? b1 : (l == 2) ? b2 : b3;
        ((float*)(ws + WS_BIAS))[b] = bl[64 * fg + 32 * ft + 8 * j + 4 * g + m];
    } else if (t < 51968) {
        int m = t - 51712;             // 0..255
        int o = m >> 7, r = m & 127;
        int j = r >> 1, p = r & 1;
        ws[WS_W4 + o * 128 + 2 * j + p] = (f16)w4[4 * j + 2 * p + o];
    }
}

// 16 individually-named weight frags per layer: no arrays, no pointers -> SROA-safe
#define WDECL(P) f16x8 P##_0,P##_1,P##_2,P##_3,P##_4,P##_5,P##_6,P##_7, \
                       P##_8,P##_9,P##_10,P##_11,P##_12,P##_13,P##_14,P##_15
#define WLOAD1(P, l, ks) \
    P##_##ks = wsv[((((l)*2+fg)*8+(ks/2))*2+(ks&1))*64+lane]
#define WLOAD(P, l) \
    WLOAD1(P,l,0);  WLOAD1(P,l,1);  WLOAD1(P,l,2);  WLOAD1(P,l,3);  \
    WLOAD1(P,l,4);  WLOAD1(P,l,5);  WLOAD1(P,l,6);  WLOAD1(P,l,7);  \
    WLOAD1(P,l,8);  WLOAD1(P,l,9);  WLOAD1(P,l,10); WLOAD1(P,l,11); \
    WLOAD1(P,l,12); WLOAD1(P,l,13); WLOAD1(P,l,14); WLOAD1(P,l,15)

#define MIDSTEP(P0, P1, ks, S) { \
    f16x8 b = *(const f16x8*)&(S)[el * 128 + 8 * ((2*(ks)+g) ^ (el & 15))]; \
    acc0 = __builtin_amdgcn_mfma_f32_32x32x16_f16(P0, b, acc0, 0, 0, 0); \
    acc1 = __builtin_amdgcn_mfma_f32_32x32x16_f16(P1, b, acc1, 0, 0, 0); }

#define MIDLAYER(P, bl, S) \
    bias_init(bl); \
    MIDSTEP(P##_0, P##_1, 0, S)  MIDSTEP(P##_2, P##_3, 1, S) \
    MIDSTEP(P##_4, P##_5, 2, S)  MIDSTEP(P##_6, P##_7, 3, S) \
    MIDSTEP(P##_8, P##_9, 4, S)  MIDSTEP(P##_10,P##_11,5, S) \
    MIDSTEP(P##_12,P##_13,6, S)  MIDSTEP(P##_14,P##_15,7, S)

__launch_bounds__(256, 2)
__global__ void gnn_mfma(const float* __restrict__ pos, const float* __restrict__ vel,
                         const float* __restrict__ a, const float* __restrict__ vnorm,
                         const float* __restrict__ b4,
                         const int* __restrict__ ei, const int* __restrict__ did,
                         const f16* __restrict__ ws, float* __restrict__ out,
                         int nNodes, int nEdges)
{
    __shared__ __align__(16) f16 A0[8192], A1[8192];   // 2 x 16 KB, 4-bit chunk-swizzle

    const int tid = threadIdx.x;
    const int lane = tid & 63;
    const int wid = tid >> 6;
    const int eg = wid & 1, fg = wid >> 1;
    const int g = lane >> 5, ln = lane & 31;
    const int el = 32 * eg + ln;

    const f16x8* wsv = (const f16x8*)ws;
    const float* wsb = (const float*)(ws + WS_BIAS);

    // ---- all mid-layer weight frags resident: 48 named f16x8 (192 VGPR) ----
    WDECL(W1); WDECL(W2); WDECL(W3);
    WLOAD(W1, 0); WLOAD(W2, 1); WLOAD(W3, 2);

    const float invn = 1.0f / vnorm[0];
    const float2* embp = (const float2*)(a + (size_t)did[0] * (size_t)nNodes * 2);
    const float b40 = b4[0], b41 = b4[1];

    f32x16 acc0, acc1;

    auto bias_init = [&](int l) {
        #pragma unroll
        for (int ft = 0; ft < 2; ++ft) {
            const float* bp = wsb + ((l * 2 + fg) * 2 + ft) * 32 + g * 16;
            #pragma unroll
            for (int j = 0; j < 4; ++j) {
                float4 bv = *(const float4*)(bp + 4 * j);
                if (ft) { acc1[4*j] = bv.x; acc1[4*j+1] = bv.y; acc1[4*j+2] = bv.z; acc1[4*j+3] = bv.w; }
                else    { acc0[4*j] = bv.x; acc0[4*j+1] = bv.y; acc0[4*j+2] = bv.z; acc0[4*j+3] = bv.w; }
            }
        }
    };

    auto writeback = [&](f16* N) {
        #pragma unroll
        for (int ft = 0; ft < 2; ++ft)
            #pragma unroll
            for (int j = 0; j < 4; ++j) {
                f16x4 hv;
                #pragma unroll
                for (int m = 0; m < 4; ++m)
                    hv[m] = (f16)fmaxf((ft ? acc1 : acc0)[4 * j + m], 0.0f);
                int c = 8 * fg + 4 * ft + j;
                *(f16x4*)&N[el * 128 + 8 * (c ^ (el & 15)) + 4 * g] = hv;
            }
    };

    const int ntiles = (nEdges + 63) >> 6;
    #pragma unroll 1
    for (int tile = blockIdx.x; tile < ntiles; tile += gridDim.x) {
        const int e0 = tile * 64;

        // ---- gather: 9 features, hi in chunks 0-1, lo in chunks 2-3 ----
        if (tid < 64) {
            int e = e0 + tid;
            int d = 0, s = 0;
            if (e < nEdges) { d = ei[e]; s = ei[nEdges + e]; }
            float2 pd = ((const float2*)pos)[d];
            float2 ps = ((const float2*)pos)[s];
            float2 vd = ((const float2*)vel)[d];
            float2 vs = ((const float2*)vel)[s];
            float2 ae = embp[d];
            float fx[9];
            fx[0] = (ps.x - pd.x) / 0.1f;
            fx[1] = (ps.y - pd.y) / 0.1f;
            fx[2] = sqrtf(fx[0] * fx[0] + fx[1] * fx[1]);
            fx[3] = vd.x * invn; fx[4] = vd.y * invn;
            fx[5] = vs.x * invn; fx[6] = vs.y * invn;
            fx[7] = ae.x; fx[8] = ae.y;
            f16x8 h0, l0, h1, l1;
            #pragma unroll
            for (int i = 0; i < 8; ++i) {
                f16 h = (f16)fx[i];
                h0[i] = h; l0[i] = (f16)(fx[i] - (float)h);
                h1[i] = (f16)0; l1[i] = (f16)0;
            }
            f16 h8 = (f16)fx[8];
            h1[0] = h8; l1[0] = (f16)(fx[8] - (float)h8);
            int er = tid;
            *(f16x8*)&A0[er * 128 + 8 * (0 ^ (er & 15))] = h0;
            *(f16x8*)&A0[er * 128 + 8 * (1 ^ (er & 15))] = h1;
            *(f16x8*)&A0[er * 128 + 8 * (2 ^ (er & 15))] = l0;
            *(f16x8*)&A0[er * 128 + 8 * (3 ^ (er & 15))] = l1;
        }
        __syncthreads();

        // ---- layer 0: K=16, input hi/lo; w0 frags re-loaded per tile (L1-hit) ----
        bias_init(0);
        {
            f16x8 w0f0 = wsv[WS_W0 / 8 + ((fg * 2 + 0) * 2 + g) * 32 + ln];
            f16x8 w0f1 = wsv[WS_W0 / 8 + ((fg * 2 + 1) * 2 + g) * 32 + ln];
            f16x8 bhi = *(const f16x8*)&A0[el * 128 + 8 * (g ^ (el & 15))];
            f16x8 blo = *(const f16x8*)&A0[el * 128 + 8 * ((2 + g) ^ (el & 15))];
            acc0 = __builtin_amdgcn_mfma_f32_32x32x16_f16(w0f0, bhi, acc0, 0, 0, 0);
            acc1 = __builtin_amdgcn_mfma_f32_32x32x16_f16(w0f1, bhi, acc1, 0, 0, 0);
            acc0 = __builtin_amdgcn_mfma_f32_32x32x16_f16(w0f0, blo, acc0, 0, 0, 0);
            acc1 = __builtin_amdgcn_mfma_f32_32x32x16_f16(w0f1, blo, acc1, 0, 0, 0);
        }
        writeback(A1);
        __syncthreads();

        MIDLAYER(W1, 1, A1);  writeback(A0);  __syncthreads();   // w1: A1 -> A0
        MIDLAYER(W2, 2, A0);  writeback(A1);  __syncthreads();   // w2: A0 -> A1
        MIDLAYER(W3, 3, A1);  writeback(A0);  __syncthreads();   // w3: A1 -> A0

        // ---- final layer 128 -> 2 via fdot2, atomic segment-sum ----
        {
            int e = tid >> 2, q = tid & 3;
            const f16x8* wp = (const f16x8*)(ws + WS_W4);
            float y0 = 0.0f, y1 = 0.0f;
            #pragma unroll
            for (int cc = 0; cc < 4; ++cc) {
                int c = 4 * q + cc;
                f16x8 hv = *(const f16x8*)&A0[e * 128 + 8 * (c ^ (e & 15))];
                f16x8 wv0 = wp[c];
                f16x8 wv1 = wp[16 + c];
                #pragma unroll
                for (int i = 0; i < 4; ++i) {
                    f16x2 xa; xa[0] = hv[2*i]; xa[1] = hv[2*i+1];
                    f16x2 wa; wa[0] = wv0[2*i]; wa[1] = wv0[2*i+1];
                    f16x2 wb; wb[0] = wv1[2*i]; wb[1] = wv1[2*i+1];
                    y0 = __builtin_amdgcn_fdot2(xa, wa, y0, false);
                    y1 = __builtin_amdgcn_fdot2(xa, wb, y1, false);
                }
            }
            y0 += __shfl_xor(y0, 1); y0 += __shfl_xor(y0, 2);
            y1 += __shfl_xor(y1, 1); y1 += __shfl_xor(y1, 2);
            int eG = e0 + e;
            if (q == 0 && eG < nEdges) {
                int d = ei[eG];
                atomicAdd(&out[2 * d],     y0 + b40);
                atomicAdd(&out[2 * d + 1], y1 + b41);
            }
        }
        __syncthreads();   // protect A0 before next tile's gather
    }
}

extern "C" void kernel_launch(void* const* d_in, const int* in_sizes, int n_in,
                              void* d_out, int out_size, void* d_ws, size_t ws_size,
                              hipStream_t stream) {
    const float* pos   = (const float*)d_in[0];
    const float* vel   = (const float*)d_in[1];
    const float* a     = (const float*)d_in[2];
    const float* vnorm = (const float*)d_in[3];
    const float* w0    = (const float*)d_in[4];
    const float* b0    = (const float*)d_in[5];
    const float* w1    = (const float*)d_in[6];
    const float* b1    = (const float*)d_in[7];
    const float* w2    = (const float*)d_in[8];
    const float* b2    = (const float*)d_in[9];
    const float* w3    = (const float*)d_in[10];
    const float* b3    = (const float*)d_in[11];
    const float* w4    = (const float*)d_in[12];
    const float* b4    = (const float*)d_in[13];
    const int*   ei    = (const int*)d_in[14];
    const int*   did   = (const int*)d_in[15];
    float* out = (float*)d_out;
    f16* ws = (f16*)d_ws;

    int nEdges = in_sizes[14] / 2;   // 800000
    int nNodes = in_sizes[0] / 2;    // 50000

    hipLaunchKernelGGL(zero_f32, dim3((out_size + 255) / 256), dim3(256), 0, stream,
                       out, out_size);
    hipLaunchKernelGGL(prep_weights, dim3(203), dim3(256), 0, stream,
                       w1, w2, w3, w0, b0, b1, b2, b3, w4, ws);
    int ntiles = (nEdges + 63) / 64;
    int grid = 512;                  // 2 blocks/CU resident, ~24 tiles each
    if (grid > ntiles) grid = ntiles;
    hipLaunchKernelGGL(gnn_mfma, dim3(grid), dim3(256), 0, stream,
                       pos, vel, a, vnorm, b4, ei, did, ws, out,
                       nNodes, nEdges);
}

// Round 8
// 522.023 us; speedup vs baseline: 1.0737x; 1.0737x over previous
//
#include <hip/hip_runtime.h>
#include <math.h>

typedef _Float16 f16;
typedef f16 f16x2 __attribute__((ext_vector_type(2)));
typedef f16 f16x8 __attribute__((ext_vector_type(8)));
typedef f16 f16x4 __attribute__((ext_vector_type(4)));
typedef float f32x16 __attribute__((ext_vector_type(16)));

// ws layout (f16 units):
//  mid W (w1,w2,w3) per-wave frags, single f16:
//    flat = (((l*2+fg)*8+ks)*2+ft)*512 + (32*g+ln)*8 + i
//  W0 frags at 49152 (2048 f16): ((fg*2+ft)*2+g)*256 + ln*8 + i (k<16, pad 0)
//  packed bias (f32) at f16-offset 53248: 512 floats
//  w4 f16 pairs at 54272: [o][128]: idx o*128+2j+p = w4[4j+2p+o]
#define WS_W0 49152
#define WS_BIAS 53248
#define WS_W4 54272

__global__ void zero_f32(float* __restrict__ p, int n) {
    int i = blockIdx.x * blockDim.x + threadIdx.x;
    if (i < n) p[i] = 0.0f;
}

__global__ void prep_weights(const float* __restrict__ w1, const float* __restrict__ w2,
                             const float* __restrict__ w3, const float* __restrict__ w0,
                             const float* __restrict__ b0, const float* __restrict__ b1,
                             const float* __restrict__ b2, const float* __restrict__ b3,
                             const float* __restrict__ w4, f16* __restrict__ ws) {
    int t = blockIdx.x * 256 + threadIdx.x;
    if (t < 49152) {
        int l = t >> 14;
        int r = t & 16383;
        int k = r >> 7, f = r & 127;
        const float* w = (l == 0) ? w1 : (l == 1) ? w2 : w3;
        float v = w[k * 128 + f];
        int fg = f >> 6, ft = (f >> 5) & 1, ln = f & 31;
        int ks = k >> 4, g = (k >> 3) & 1, i = k & 7;
        ws[(((l * 2 + fg) * 8 + ks) * 2 + ft) * 512 + (32 * g + ln) * 8 + i] = (f16)v;
    } else if (t < 51200) {
        int r = t - 49152;
        int k = r >> 7, f = r & 127;   // k 0..15
        float v = (k < 9) ? w0[k * 128 + f] : 0.0f;
        int fg = f >> 6, ft = (f >> 5) & 1, ln = f & 31;
        int g = (k >> 3) & 1, i = k & 7;
        ws[WS_W0 + ((fg * 2 + ft) * 2 + g) * 256 + ln * 8 + i] = (f16)v;
    } else if (t < 51712) {
        int b = t - 51200;             // 0..511
        int l = b >> 7, r = b & 127;
        int fg = r >> 6, ft = (r >> 5) & 1, g = (r >> 4) & 1, j = (r >> 2) & 3, m = r & 3;
        const float* bl = (l == 0) ? b0 : (l == 1) ? b1 : (l == 2) ? b2 : b3;
        ((float*)(ws + WS_BIAS))[b] = bl[64 * fg + 32 * ft + 8 * j + 4 * g + m];
    } else if (t < 51968) {
        int m = t - 51712;             // 0..255
        int o = m >> 7, r = m & 127;
        int j = r >> 1, p = r & 1;
        ws[WS_W4 + o * 128 + 2 * j + p] = (f16)w4[4 * j + 2 * p + o];
    }
}

// 16 individually-named weight frags per layer: no arrays, no pointers -> SROA-safe
#define WDECL(P) f16x8 P##_0,P##_1,P##_2,P##_3,P##_4,P##_5,P##_6,P##_7, \
                       P##_8,P##_9,P##_10,P##_11,P##_12,P##_13,P##_14,P##_15
#define WLOAD1(P, l, ks) \
    P##_##ks = wsv[((((l)*2+fg)*8+(ks/2))*2+(ks&1))*64+lane]
#define WLOAD(P, l) \
    WLOAD1(P,l,0);  WLOAD1(P,l,1);  WLOAD1(P,l,2);  WLOAD1(P,l,3);  \
    WLOAD1(P,l,4);  WLOAD1(P,l,5);  WLOAD1(P,l,6);  WLOAD1(P,l,7);  \
    WLOAD1(P,l,8);  WLOAD1(P,l,9);  WLOAD1(P,l,10); WLOAD1(P,l,11); \
    WLOAD1(P,l,12); WLOAD1(P,l,13); WLOAD1(P,l,14); WLOAD1(P,l,15)

#define MIDSTEP(P0, P1, ks, S) { \
    f16x8 b = *(const f16x8*)&(S)[el * 128 + 8 * ((2*(ks)+g) ^ (el & 15))]; \
    acc0 = __builtin_amdgcn_mfma_f32_32x32x16_f16(P0, b, acc0, 0, 0, 0); \
    acc1 = __builtin_amdgcn_mfma_f32_32x32x16_f16(P1, b, acc1, 0, 0, 0); }

#define MIDLAYER(P, bl, S) \
    bias_init(bl); \
    MIDSTEP(P##_0, P##_1, 0, S)  MIDSTEP(P##_2, P##_3, 1, S) \
    MIDSTEP(P##_4, P##_5, 2, S)  MIDSTEP(P##_6, P##_7, 3, S) \
    MIDSTEP(P##_8, P##_9, 4, S)  MIDSTEP(P##_10,P##_11,5, S) \
    MIDSTEP(P##_12,P##_13,6, S)  MIDSTEP(P##_14,P##_15,7, S)

__global__ __attribute__((amdgpu_flat_work_group_size(256, 256), amdgpu_waves_per_eu(2, 2)))
void gnn_mfma(const float* __restrict__ pos, const float* __restrict__ vel,
              const float* __restrict__ a, const float* __restrict__ vnorm,
              const float* __restrict__ b4,
              const int* __restrict__ ei, const int* __restrict__ did,
              const f16* __restrict__ ws, float* __restrict__ out,
              int nNodes, int nEdges)
{
    __shared__ __align__(16) f16 A0[8192], A1[8192];   // 2 x 16 KB, 4-bit chunk-swizzle

    const int tid = threadIdx.x;
    const int lane = tid & 63;
    const int wid = tid >> 6;
    const int eg = wid & 1, fg = wid >> 1;
    const int g = lane >> 5, ln = lane & 31;
    const int el = 32 * eg + ln;

    const f16x8* wsv = (const f16x8*)ws;
    const float* wsb = (const float*)(ws + WS_BIAS);

    // ---- all mid-layer weight frags resident: 48 named f16x8 (192 VGPR) ----
    WDECL(W1); WDECL(W2); WDECL(W3);
    WLOAD(W1, 0); WLOAD(W2, 1); WLOAD(W3, 2);

    const float invn = 1.0f / vnorm[0];
    const float2* embp = (const float2*)(a + (size_t)did[0] * (size_t)nNodes * 2);
    const float b40 = b4[0], b41 = b4[1];

    f32x16 acc0, acc1;

    auto bias_init = [&](int l) {
        #pragma unroll
        for (int ft = 0; ft < 2; ++ft) {
            const float* bp = wsb + ((l * 2 + fg) * 2 + ft) * 32 + g * 16;
            #pragma unroll
            for (int j = 0; j < 4; ++j) {
                float4 bv = *(const float4*)(bp + 4 * j);
                if (ft) { acc1[4*j] = bv.x; acc1[4*j+1] = bv.y; acc1[4*j+2] = bv.z; acc1[4*j+3] = bv.w; }
                else    { acc0[4*j] = bv.x; acc0[4*j+1] = bv.y; acc0[4*j+2] = bv.z; acc0[4*j+3] = bv.w; }
            }
        }
    };

    auto writeback = [&](f16* N) {
        #pragma unroll
        for (int ft = 0; ft < 2; ++ft)
            #pragma unroll
            for (int j = 0; j < 4; ++j) {
                f16x4 hv;
                #pragma unroll
                for (int m = 0; m < 4; ++m)
                    hv[m] = (f16)fmaxf((ft ? acc1 : acc0)[4 * j + m], 0.0f);
                int c = 8 * fg + 4 * ft + j;
                *(f16x4*)&N[el * 128 + 8 * (c ^ (el & 15)) + 4 * g] = hv;
            }
    };

    const int ntiles = (nEdges + 63) >> 6;
    #pragma unroll 1
    for (int tile = blockIdx.x; tile < ntiles; tile += gridDim.x) {
        const int e0 = tile * 64;

        // ---- gather: 9 features, hi in chunks 0-1, lo in chunks 2-3 ----
        if (tid < 64) {
            int e = e0 + tid;
            int d = 0, s = 0;
            if (e < nEdges) { d = ei[e]; s = ei[nEdges + e]; }
            float2 pd = ((const float2*)pos)[d];
            float2 ps = ((const float2*)pos)[s];
            float2 vd = ((const float2*)vel)[d];
            float2 vs = ((const float2*)vel)[s];
            float2 ae = embp[d];
            float fx[9];
            fx[0] = (ps.x - pd.x) / 0.1f;
            fx[1] = (ps.y - pd.y) / 0.1f;
            fx[2] = sqrtf(fx[0] * fx[0] + fx[1] * fx[1]);
            fx[3] = vd.x * invn; fx[4] = vd.y * invn;
            fx[5] = vs.x * invn; fx[6] = vs.y * invn;
            fx[7] = ae.x; fx[8] = ae.y;
            f16x8 h0, l0, h1, l1;
            #pragma unroll
            for (int i = 0; i < 8; ++i) {
                f16 h = (f16)fx[i];
                h0[i] = h; l0[i] = (f16)(fx[i] - (float)h);
                h1[i] = (f16)0; l1[i] = (f16)0;
            }
            f16 h8 = (f16)fx[8];
            h1[0] = h8; l1[0] = (f16)(fx[8] - (float)h8);
            int er = tid;
            *(f16x8*)&A0[er * 128 + 8 * (0 ^ (er & 15))] = h0;
            *(f16x8*)&A0[er * 128 + 8 * (1 ^ (er & 15))] = h1;
            *(f16x8*)&A0[er * 128 + 8 * (2 ^ (er & 15))] = l0;
            *(f16x8*)&A0[er * 128 + 8 * (3 ^ (er & 15))] = l1;
        }
        __syncthreads();

        // ---- layer 0: K=16, input hi/lo; w0 frags re-loaded per tile (L1-hit) ----
        bias_init(0);
        {
            f16x8 w0f0 = wsv[WS_W0 / 8 + ((fg * 2 + 0) * 2 + g) * 32 + ln];
            f16x8 w0f1 = wsv[WS_W0 / 8 + ((fg * 2 + 1) * 2 + g) * 32 + ln];
            f16x8 bhi = *(const f16x8*)&A0[el * 128 + 8 * (g ^ (el & 15))];
            f16x8 blo = *(const f16x8*)&A0[el * 128 + 8 * ((2 + g) ^ (el & 15))];
            acc0 = __builtin_amdgcn_mfma_f32_32x32x16_f16(w0f0, bhi, acc0, 0, 0, 0);
            acc1 = __builtin_amdgcn_mfma_f32_32x32x16_f16(w0f1, bhi, acc1, 0, 0, 0);
            acc0 = __builtin_amdgcn_mfma_f32_32x32x16_f16(w0f0, blo, acc0, 0, 0, 0);
            acc1 = __builtin_amdgcn_mfma_f32_32x32x16_f16(w0f1, blo, acc1, 0, 0, 0);
        }
        writeback(A1);
        __syncthreads();

        MIDLAYER(W1, 1, A1);  writeback(A0);  __syncthreads();   // w1: A1 -> A0
        MIDLAYER(W2, 2, A0);  writeback(A1);  __syncthreads();   // w2: A0 -> A1
        MIDLAYER(W3, 3, A1);  writeback(A0);  __syncthreads();   // w3: A1 -> A0

        // ---- final layer 128 -> 2 via fdot2, atomic segment-sum ----
        {
            int e = tid >> 2, q = tid & 3;
            const f16x8* wp = (const f16x8*)(ws + WS_W4);
            float y0 = 0.0f, y1 = 0.0f;
            #pragma unroll
            for (int cc = 0; cc < 4; ++cc) {
                int c = 4 * q + cc;
                f16x8 hv = *(const f16x8*)&A0[e * 128 + 8 * (c ^ (e & 15))];
                f16x8 wv0 = wp[c];
                f16x8 wv1 = wp[16 + c];
                #pragma unroll
                for (int i = 0; i < 4; ++i) {
                    f16x2 xa; xa[0] = hv[2*i]; xa[1] = hv[2*i+1];
                    f16x2 wa; wa[0] = wv0[2*i]; wa[1] = wv0[2*i+1];
                    f16x2 wb; wb[0] = wv1[2*i]; wb[1] = wv1[2*i+1];
                    y0 = __builtin_amdgcn_fdot2(xa, wa, y0, false);
                    y1 = __builtin_amdgcn_fdot2(xa, wb, y1, false);
                }
            }
            y0 += __shfl_xor(y0, 1); y0 += __shfl_xor(y0, 2);
            y1 += __shfl_xor(y1, 1); y1 += __shfl_xor(y1, 2);
            int eG = e0 + e;
            if (q == 0 && eG < nEdges) {
                int d = ei[eG];
                atomicAdd(&out[2 * d],     y0 + b40);
                atomicAdd(&out[2 * d + 1], y1 + b41);
            }
        }
        __syncthreads();   // protect A0 before next tile's gather
    }
}

extern "C" void kernel_launch(void* const* d_in, const int* in_sizes, int n_in,
                              void* d_out, int out_size, void* d_ws, size_t ws_size,
                              hipStream_t stream) {
    const float* pos   = (const float*)d_in[0];
    const float* vel   = (const float*)d_in[1];
    const float* a     = (const float*)d_in[2];
    const float* vnorm = (const float*)d_in[3];
    const float* w0    = (const float*)d_in[4];
    const float* b0    = (const float*)d_in[5];
    const float* w1    = (const float*)d_in[6];
    const float* b1    = (const float*)d_in[7];
    const float* w2    = (const float*)d_in[8];
    const float* b2    = (const float*)d_in[9];
    const float* w3    = (const float*)d_in[10];
    const float* b3    = (const float*)d_in[11];
    const float* w4    = (const float*)d_in[12];
    const float* b4    = (const float*)d_in[13];
    const int*   ei    = (const int*)d_in[14];
    const int*   did   = (const int*)d_in[15];
    float* out = (float*)d_out;
    f16* ws = (f16*)d_ws;

    int nEdges = in_sizes[14] / 2;   // 800000
    int nNodes = in_sizes[0] / 2;    // 50000

    hipLaunchKernelGGL(zero_f32, dim3((out_size + 255) / 256), dim3(256), 0, stream,
                       out, out_size);
    hipLaunchKernelGGL(prep_weights, dim3(203), dim3(256), 0, stream,
                       w1, w2, w3, w0, b0, b1, b2, b3, w4, ws);
    int ntiles = (nEdges + 63) / 64;
    int grid = 512;                  // 2 blocks/CU resident, ~24 tiles each
    if (grid > ntiles) grid = ntiles;
    hipLaunchKernelGGL(gnn_mfma, dim3(grid), dim3(256), 0, stream,
                       pos, vel, a, vnorm, b4, ei, did, ws, out,
                       nNodes, nEdges);
}

// Round 9
// 194.958 us; speedup vs baseline: 2.8749x; 2.6776x over previous
//
#include <hip/hip_runtime.h>
#include <math.h>

typedef _Float16 f16;
typedef f16 f16x8 __attribute__((ext_vector_type(8)));
typedef f16 f16x4 __attribute__((ext_vector_type(4)));
typedef float f32x16 __attribute__((ext_vector_type(16)));

// ws layout (f16 units):
//  mid W (w1,w2,w3) per-wave frags, single f16:
//    flat = (((l*2+fg)*8+ks)*2+ft)*512 + (32*g+ln)*8 + i   (f=64fg+32ft+ln, k=16ks+8g+i)
//  W0 frags at 49152 (2048 f16): ((fg*2+ft)*2+g)*256 + ln*8 + i (k<16, pad 0)
//  packed bias (f32) at f16-offset 53248: 512 floats:
//    idx = ((l*2+fg)*2+ft)*32 + g*16 + 4*j + m = b_l[64fg+32ft+8j+4g+m]
//  w4 A-frags at 54272 (4096 f16): frag[ks] elem(lane=32g+ln, i) =
//    (ln<2) ? w4[(16ks+8g+i)*2 + ln] : 0
#define WS_W0 49152
#define WS_BIAS 53248
#define WS_W4F 54272

__global__ void zero_f32(float* __restrict__ p, int n) {
    int i = blockIdx.x * blockDim.x + threadIdx.x;
    if (i < n) p[i] = 0.0f;
}

__global__ void prep_weights(const float* __restrict__ w1, const float* __restrict__ w2,
                             const float* __restrict__ w3, const float* __restrict__ w0,
                             const float* __restrict__ b0, const float* __restrict__ b1,
                             const float* __restrict__ b2, const float* __restrict__ b3,
                             const float* __restrict__ w4, f16* __restrict__ ws) {
    int t = blockIdx.x * 256 + threadIdx.x;
    if (t < 49152) {
        int l = t >> 14;
        int r = t & 16383;
        int k = r >> 7, f = r & 127;
        const float* w = (l == 0) ? w1 : (l == 1) ? w2 : w3;
        float v = w[k * 128 + f];
        int fg = f >> 6, ft = (f >> 5) & 1, ln = f & 31;
        int ks = k >> 4, g = (k >> 3) & 1, i = k & 7;
        ws[(((l * 2 + fg) * 8 + ks) * 2 + ft) * 512 + (32 * g + ln) * 8 + i] = (f16)v;
    } else if (t < 51200) {
        int r = t - 49152;
        int k = r >> 7, f = r & 127;   // k 0..15
        float v = (k < 9) ? w0[k * 128 + f] : 0.0f;
        int fg = f >> 6, ft = (f >> 5) & 1, ln = f & 31;
        int g = (k >> 3) & 1, i = k & 7;
        ws[WS_W0 + ((fg * 2 + ft) * 2 + g) * 256 + ln * 8 + i] = (f16)v;
    } else if (t < 51712) {
        int b = t - 51200;             // 0..511
        int l = b >> 7, r = b & 127;
        int fg = r >> 6, ft = (r >> 5) & 1, g = (r >> 4) & 1, j = (r >> 2) & 3, m = r & 3;
        const float* bl = (l == 0) ? b0 : (l == 1) ? b1 : (l == 2) ? b2 : b3;
        ((float*)(ws + WS_BIAS))[b] = bl[64 * fg + 32 * ft + 8 * j + 4 * g + m];
    } else if (t < 55808) {
        int m = t - 51712;             // 0..4095
        int ks = m >> 9, r = m & 511;
        int lane = r >> 3, i = r & 7;
        int g = lane >> 5, ln = lane & 31;
        int k = 16 * ks + 8 * g + i;
        ws[WS_W4F + m] = (ln < 2) ? (f16)w4[k * 2 + ln] : (f16)0;
    }
}

__launch_bounds__(512, 2)
__global__ void gnn_mfma(const float* __restrict__ pos, const float* __restrict__ vel,
                         const float* __restrict__ a, const float* __restrict__ vnorm,
                         const float* __restrict__ b4,
                         const int* __restrict__ ei, const int* __restrict__ did,
                         const f16* __restrict__ ws, float* __restrict__ out,
                         int nNodes, int nEdges)
{
    __shared__ __align__(16) f16 A0[16384], A1[16384];   // 2 x 32 KB, 4-bit chunk-swizzle

    const int tid = threadIdx.x;
    const int lane = tid & 63;
    const int wid = tid >> 6;
    const int eg = wid & 3, fg = wid >> 2;
    const int g = lane >> 5, ln = lane & 31;
    const int el = 32 * eg + ln;
    const int e0 = blockIdx.x * 128;

    const f16x8* wsv = (const f16x8*)ws;
    const float* wsb = (const float*)(ws + WS_BIAS);

    // current-layer W frags (compiler may sink/reload from L1/L2 — that's fine)
    f16x8 W[16];
    #pragma unroll
    for (int ks = 0; ks < 8; ++ks)
        #pragma unroll
        for (int ft = 0; ft < 2; ++ft)
            W[ks * 2 + ft] = wsv[(((0 * 2 + fg) * 8 + ks) * 2 + ft) * 64 + lane];

    f16x8 w0f0 = wsv[WS_W0 / 8 + ((fg * 2 + 0) * 2 + g) * 32 + ln];
    f16x8 w0f1 = wsv[WS_W0 / 8 + ((fg * 2 + 1) * 2 + g) * 32 + ln];

    // ---- gather: 128 edges, 9 features; hi in chunks 0-1, lo in chunks 2-3 ----
    if (tid < 128) {
        int e = e0 + tid;
        int d = 0, s = 0;
        if (e < nEdges) { d = ei[e]; s = ei[nEdges + e]; }
        float2 pd = ((const float2*)pos)[d];
        float2 ps = ((const float2*)pos)[s];
        float2 vd = ((const float2*)vel)[d];
        float2 vs = ((const float2*)vel)[s];
        const float2* embp = (const float2*)(a + (size_t)did[0] * (size_t)nNodes * 2);
        float2 ae = embp[d];
        float invn = 1.0f / vnorm[0];
        float fx[9];
        fx[0] = (ps.x - pd.x) / 0.1f;
        fx[1] = (ps.y - pd.y) / 0.1f;
        fx[2] = sqrtf(fx[0] * fx[0] + fx[1] * fx[1]);
        fx[3] = vd.x * invn; fx[4] = vd.y * invn;
        fx[5] = vs.x * invn; fx[6] = vs.y * invn;
        fx[7] = ae.x; fx[8] = ae.y;
        f16x8 h0, l0, h1, l1;
        #pragma unroll
        for (int i = 0; i < 8; ++i) {
            f16 h = (f16)fx[i];
            h0[i] = h; l0[i] = (f16)(fx[i] - (float)h);
            h1[i] = (f16)0; l1[i] = (f16)0;
        }
        f16 h8 = (f16)fx[8];
        h1[0] = h8; l1[0] = (f16)(fx[8] - (float)h8);
        int er = tid;
        *(f16x8*)&A0[er * 128 + 8 * (0 ^ (er & 15))] = h0;
        *(f16x8*)&A0[er * 128 + 8 * (1 ^ (er & 15))] = h1;
        *(f16x8*)&A0[er * 128 + 8 * (2 ^ (er & 15))] = l0;
        *(f16x8*)&A0[er * 128 + 8 * (3 ^ (er & 15))] = l1;
    }
    __syncthreads();

    f32x16 acc0, acc1;

    auto bias_init = [&](int l) {
        #pragma unroll
        for (int ft = 0; ft < 2; ++ft) {
            const float* bp = wsb + ((l * 2 + fg) * 2 + ft) * 32 + g * 16;
            #pragma unroll
            for (int j = 0; j < 4; ++j) {
                float4 bv = *(const float4*)(bp + 4 * j);
                if (ft) { acc1[4*j] = bv.x; acc1[4*j+1] = bv.y; acc1[4*j+2] = bv.z; acc1[4*j+3] = bv.w; }
                else    { acc0[4*j] = bv.x; acc0[4*j+1] = bv.y; acc0[4*j+2] = bv.z; acc0[4*j+3] = bv.w; }
            }
        }
    };

    // ReLU in packed f16: round-then-clamp == clamp-then-round for ReLU
    auto writeback = [&](f16* N) {
        #pragma unroll
        for (int ft = 0; ft < 2; ++ft)
            #pragma unroll
            for (int j = 0; j < 4; ++j) {
                f16x4 hv;
                #pragma unroll
                for (int m = 0; m < 4; ++m)
                    hv[m] = (f16)((ft ? acc1 : acc0)[4 * j + m]);
                f16x4 z = {(f16)0, (f16)0, (f16)0, (f16)0};
                hv = __builtin_elementwise_max(hv, z);
                int c = 8 * fg + 4 * ft + j;
                *(f16x4*)&N[el * 128 + 8 * (c ^ (el & 15)) + 4 * g] = hv;
            }
    };

    // ---- layer 0: K=16, input hi/lo ----
    bias_init(0);
    {
        f16x8 bhi = *(const f16x8*)&A0[el * 128 + 8 * (g ^ (el & 15))];
        f16x8 blo = *(const f16x8*)&A0[el * 128 + 8 * ((2 + g) ^ (el & 15))];
        acc0 = __builtin_amdgcn_mfma_f32_32x32x16_f16(w0f0, bhi, acc0, 0, 0, 0);
        acc1 = __builtin_amdgcn_mfma_f32_32x32x16_f16(w0f1, bhi, acc1, 0, 0, 0);
        acc0 = __builtin_amdgcn_mfma_f32_32x32x16_f16(w0f0, blo, acc0, 0, 0, 0);
        acc1 = __builtin_amdgcn_mfma_f32_32x32x16_f16(w0f1, blo, acc1, 0, 0, 0);
    }
    writeback(A1);
    __syncthreads();

    auto midlayer = [&](int l, const f16* S) {
        bias_init(l);
        #pragma unroll
        for (int ks = 0; ks < 8; ++ks) {
            f16x8 b = *(const f16x8*)&S[el * 128 + 8 * ((2 * ks + g) ^ (el & 15))];
            acc0 = __builtin_amdgcn_mfma_f32_32x32x16_f16(W[ks * 2 + 0], b, acc0, 0, 0, 0);
            acc1 = __builtin_amdgcn_mfma_f32_32x32x16_f16(W[ks * 2 + 1], b, acc1, 0, 0, 0);
        }
    };

    midlayer(1, A1);                   // w1: A1 -> A0
    #pragma unroll
    for (int ks = 0; ks < 8; ++ks)     // prefetch w2
        #pragma unroll
        for (int ft = 0; ft < 2; ++ft)
            W[ks * 2 + ft] = wsv[(((1 * 2 + fg) * 8 + ks) * 2 + ft) * 64 + lane];
    writeback(A0);
    __syncthreads();

    midlayer(2, A0);                   // w2: A0 -> A1
    #pragma unroll
    for (int ks = 0; ks < 8; ++ks)     // prefetch w3
        #pragma unroll
        for (int ft = 0; ft < 2; ++ft)
            W[ks * 2 + ft] = wsv[(((2 * 2 + fg) * 8 + ks) * 2 + ft) * 64 + lane];
    writeback(A1);
    __syncthreads();

    midlayer(3, A1);                   // w3: A1 -> A0
    writeback(A0);
    __syncthreads();

    // ---- final layer 128 -> 2 via MFMA (fg==0 waves only) ----
    if (fg == 0) {
        const float b40 = b4[0], b41 = b4[1];
        f32x16 acc;
        #pragma unroll
        for (int r = 0; r < 16; ++r) acc[r] = 0.0f;
        acc[0] = b40; acc[1] = b41;     // C rows 0,1 (g==0 lanes) = bias
        #pragma unroll
        for (int ks = 0; ks < 8; ++ks) {
            f16x8 wf = wsv[WS_W4F / 8 + ks * 64 + lane];
            f16x8 b = *(const f16x8*)&A0[el * 128 + 8 * ((2 * ks + g) ^ (el & 15))];
            acc = __builtin_amdgcn_mfma_f32_32x32x16_f16(wf, b, acc, 0, 0, 0);
        }
        int e = e0 + el;
        if (g == 0 && e < nEdges) {
            int d = ei[e];
            atomicAdd(&out[2 * d],     acc[0]);
            atomicAdd(&out[2 * d + 1], acc[1]);
        }
    }
}

extern "C" void kernel_launch(void* const* d_in, const int* in_sizes, int n_in,
                              void* d_out, int out_size, void* d_ws, size_t ws_size,
                              hipStream_t stream) {
    const float* pos   = (const float*)d_in[0];
    const float* vel   = (const float*)d_in[1];
    const float* a     = (const float*)d_in[2];
    const float* vnorm = (const float*)d_in[3];
    const float* w0    = (const float*)d_in[4];
    const float* b0    = (const float*)d_in[5];
    const float* w1    = (const float*)d_in[6];
    const float* b1    = (const float*)d_in[7];
    const float* w2    = (const float*)d_in[8];
    const float* b2    = (const float*)d_in[9];
    const float* w3    = (const float*)d_in[10];
    const float* b3    = (const float*)d_in[11];
    const float* w4    = (const float*)d_in[12];
    const float* b4    = (const float*)d_in[13];
    const int*   ei    = (const int*)d_in[14];
    const int*   did   = (const int*)d_in[15];
    float* out = (float*)d_out;
    f16* ws = (f16*)d_ws;

    int nEdges = in_sizes[14] / 2;   // 800000
    int nNodes = in_sizes[0] / 2;    // 50000

    hipLaunchKernelGGL(zero_f32, dim3((out_size + 255) / 256), dim3(256), 0, stream,
                       out, out_size);
    hipLaunchKernelGGL(prep_weights, dim3(218), dim3(256), 0, stream,
                       w1, w2, w3, w0, b0, b1, b2, b3, w4, ws);
    int ntiles = (nEdges + 127) / 128;
    hipLaunchKernelGGL(gnn_mfma, dim3(ntiles), dim3(512), 0, stream,
                       pos, vel, a, vnorm, b4, ei, did, ws, out,
                       nNodes, nEdges);
}

// Round 10
// 117.417 us; speedup vs baseline: 4.7734x; 1.6604x over previous
//
#include <hip/hip_runtime.h>
#include <math.h>

typedef _Float16 f16;
typedef __fp16 h2 __attribute__((ext_vector_type(2)));
typedef f16 f16x8 __attribute__((ext_vector_type(8)));
typedef float f32x16 __attribute__((ext_vector_type(16)));

// ws / LDS layout (f16 units), identical in global ws and staged LDS:
//  LW(l) = l*16384, l=0,1,2 for w1,w2,w3: [fb][ks][lane][i] = fb*4096+ks*512+lane*8+i
//     element = w[F(ks,g,i)][32*fb+ln]   (pi-permuted k-dim, lane=32g+ln)
//  W0F = 49152 (2048): [fb][lane][i], k = 8g+i (raw input feats, k<9 else 0)
//  W4F = 51200 (4096): [ks][lane][i], rows = ln<2 ? ln : zero-pad, pi-permuted k
//  BIASF = 55296 (1024 f16 = 512 f32): [l][fb][g][j].m = b_l[32fb + m + 8j + 4g]
//  pad to 57344 f16 (114688 B)
#define LW0 0
#define LW1 16384
#define LW2 32768
#define W0F 49152
#define W4F 51200
#define BIASF 55296
#define WS_F16 57344

__global__ void zero_f32(float* __restrict__ p, int n) {
    int i = blockIdx.x * blockDim.x + threadIdx.x;
    if (i < n) p[i] = 0.0f;
}

__global__ void prep_weights(const float* __restrict__ w1, const float* __restrict__ w2,
                             const float* __restrict__ w3, const float* __restrict__ w0,
                             const float* __restrict__ b0, const float* __restrict__ b1,
                             const float* __restrict__ b2, const float* __restrict__ b3,
                             const float* __restrict__ w4, f16* __restrict__ ws) {
    int t = blockIdx.x * 256 + threadIdx.x;
    if (t < 49152) {                     // w1,w2,w3 A-frags, pi-permuted k
        int l = t >> 14, rem = t & 16383;
        int fb = rem >> 12, ks = (rem >> 9) & 7, lane = (rem >> 3) & 63, i = rem & 7;
        int g = lane >> 5, ln = lane & 31;
        int F = 32 * (ks >> 1) + (i & 3) + 8 * (2 * (ks & 1) + (i >> 2)) + 4 * g;
        const float* w = (l == 0) ? w1 : (l == 1) ? w2 : w3;
        ws[t] = (f16)w[F * 128 + 32 * fb + ln];
    } else if (t < 51200) {              // w0 A-frags, raw k
        int rem = t - 49152;
        int fb = rem >> 9, lane = (rem >> 3) & 63, i = rem & 7;
        int g = lane >> 5, ln = lane & 31;
        int k = 8 * g + i;
        ws[t] = (k < 9) ? (f16)w0[k * 128 + 32 * fb + ln] : (f16)0;
    } else if (t < 55296) {              // w4 A-frags, pi-permuted k
        int rem = t - 51200;
        int ks = rem >> 9, lane = (rem >> 3) & 63, i = rem & 7;
        int g = lane >> 5, ln = lane & 31;
        int F = 32 * (ks >> 1) + (i & 3) + 8 * (2 * (ks & 1) + (i >> 2)) + 4 * g;
        ws[t] = (ln < 2) ? (f16)w4[F * 2 + ln] : (f16)0;
    } else if (t < 57344) {              // pad (bias bytes written below as floats)
        if (t >= 56320) ws[t] = (f16)0;
    } else if (t < 57856) {              // packed bias floats
        int b = t - 57344;
        int l = b >> 7, r = b & 127;
        int fb = r >> 5, g = (r >> 4) & 1, j = (r >> 2) & 3, m = r & 3;
        const float* bl = (l == 0) ? b0 : (l == 1) ? b1 : (l == 2) ? b2 : b3;
        ((float*)(ws + BIASF))[b] = bl[32 * fb + m + 8 * j + 4 * g];
    }
}

#define MF(w, b, c) __builtin_amdgcn_mfma_f32_32x32x16_f16(w, b, c, 0, 0, 0)

#define BIASLD(acc, l, fb) {                                                   \
    const float4* bp = (const float4*)(lds + BIASF) + (((l) * 4 + (fb)) * 2 + g) * 4; \
    float4 q0 = bp[0], q1 = bp[1], q2 = bp[2], q3 = bp[3];                     \
    acc[0]=q0.x; acc[1]=q0.y; acc[2]=q0.z; acc[3]=q0.w;                        \
    acc[4]=q1.x; acc[5]=q1.y; acc[6]=q1.z; acc[7]=q1.w;                        \
    acc[8]=q2.x; acc[9]=q2.y; acc[10]=q2.z; acc[11]=q2.w;                      \
    acc[12]=q3.x; acc[13]=q3.y; acc[14]=q3.z; acc[15]=q3.w; }

// ReLU + RTZ-pack acc[8b..8b+7] -> one B-fragment (local by pi-construction)
#define PACKB(dst, acc, b) {                                                   \
    h2 z2; z2[0] = (__fp16)0; z2[1] = (__fp16)0;                               \
    h2 p0 = __builtin_elementwise_max(__builtin_amdgcn_cvt_pkrtz(acc[8*(b)+0], acc[8*(b)+1]), z2); \
    h2 p1 = __builtin_elementwise_max(__builtin_amdgcn_cvt_pkrtz(acc[8*(b)+2], acc[8*(b)+3]), z2); \
    h2 p2 = __builtin_elementwise_max(__builtin_amdgcn_cvt_pkrtz(acc[8*(b)+4], acc[8*(b)+5]), z2); \
    h2 p3 = __builtin_elementwise_max(__builtin_amdgcn_cvt_pkrtz(acc[8*(b)+6], acc[8*(b)+7]), z2); \
    dst[0]=p0[0]; dst[1]=p0[1]; dst[2]=p1[0]; dst[3]=p1[1];                    \
    dst[4]=p2[0]; dst[5]=p2[1]; dst[6]=p3[0]; dst[7]=p3[1]; }

#define MIDFB(LBASE, l, fb, B0,B1,B2,B3,B4,B5,B6,B7, O0, O1) {                 \
    f32x16 acc; BIASLD(acc, l, fb);                                            \
    const f16* wb = lds + (LBASE) + (fb) * 4096 + lane * 8;                    \
    f16x8 w;                                                                   \
    w = *(const f16x8*)(wb + 0*512); acc = MF(w, B0, acc);                     \
    w = *(const f16x8*)(wb + 1*512); acc = MF(w, B1, acc);                     \
    w = *(const f16x8*)(wb + 2*512); acc = MF(w, B2, acc);                     \
    w = *(const f16x8*)(wb + 3*512); acc = MF(w, B3, acc);                     \
    w = *(const f16x8*)(wb + 4*512); acc = MF(w, B4, acc);                     \
    w = *(const f16x8*)(wb + 5*512); acc = MF(w, B5, acc);                     \
    w = *(const f16x8*)(wb + 6*512); acc = MF(w, B6, acc);                     \
    w = *(const f16x8*)(wb + 7*512); acc = MF(w, B7, acc);                     \
    PACKB(O0, acc, 0); PACKB(O1, acc, 1); }

#define MIDLAYER(LBASE, l, I0,I1,I2,I3,I4,I5,I6,I7, O0,O1,O2,O3,O4,O5,O6,O7)   \
    MIDFB(LBASE, l, 0, I0,I1,I2,I3,I4,I5,I6,I7, O0, O1);                       \
    MIDFB(LBASE, l, 1, I0,I1,I2,I3,I4,I5,I6,I7, O2, O3);                       \
    MIDFB(LBASE, l, 2, I0,I1,I2,I3,I4,I5,I6,I7, O4, O5);                       \
    MIDFB(LBASE, l, 3, I0,I1,I2,I3,I4,I5,I6,I7, O6, O7);

#define L0FB(fb, O0, O1) {                                                     \
    f32x16 acc; BIASLD(acc, 0, fb);                                            \
    f16x8 w = *(const f16x8*)(lds + W0F + (fb) * 512 + lane * 8);              \
    acc = MF(w, bh, acc); acc = MF(w, blo, acc);                               \
    PACKB(O0, acc, 0); PACKB(O1, acc, 1); }

__launch_bounds__(1024, 4)
__global__ void gnn_mfma(const float* __restrict__ pos, const float* __restrict__ vel,
                         const float* __restrict__ a, const float* __restrict__ vnorm,
                         const float* __restrict__ b4,
                         const int* __restrict__ ei, const int* __restrict__ did,
                         const f16* __restrict__ ws, float* __restrict__ out,
                         int nNodes, int nEdges)
{
    extern __shared__ __align__(16) f16 lds[];

    const int tid = threadIdx.x;
    const int lane = tid & 63;
    const int wid = tid >> 6;
    const int g = lane >> 5;
    const int c = lane & 31;

    // ---- stage all weights+bias into LDS (one barrier, then none) ----
    {
        const f16x8* wv = (const f16x8*)ws;
        f16x8* lv = (f16x8*)lds;
        #pragma unroll
        for (int it = 0; it < 7; ++it) lv[it * 1024 + tid] = wv[it * 1024 + tid];
    }
    __syncthreads();

    const int chunk = blockIdx.x * 16 + wid;
    if (chunk >= (nEdges >> 5)) return;    // 800000/32 = 25000 chunks exact

    // ---- gather: one edge per col, loads on g==0 half only ----
    float fx0=0,fx1=0,fx2=0,fx3=0,fx4=0,fx5=0,fx6=0,fx7=0,fx8=0;
    int dsti = 0;
    const int e = chunk * 32 + c;
    if (g == 0) {
        dsti = ei[e];
        int srci = ei[nEdges + e];
        float2 pd = ((const float2*)pos)[dsti];
        float2 ps = ((const float2*)pos)[srci];
        float2 vd = ((const float2*)vel)[dsti];
        float2 vs = ((const float2*)vel)[srci];
        const float2* embp = (const float2*)(a + (size_t)did[0] * (size_t)nNodes * 2);
        float2 ae = embp[dsti];
        float invn = 1.0f / vnorm[0];
        fx0 = (ps.x - pd.x) / 0.1f;
        fx1 = (ps.y - pd.y) / 0.1f;
        fx2 = sqrtf(fx0 * fx0 + fx1 * fx1);
        fx3 = vd.x * invn; fx4 = vd.y * invn;
        fx5 = vs.x * invn; fx6 = vs.y * invn;
        fx7 = ae.x; fx8 = ae.y;
    }
    float ay = __shfl(fx8, c);             // g==1 half needs feat8 (k=8) of its col

    f16x8 bh, blo;
    #pragma unroll
    for (int i = 0; i < 8; ++i) { bh[i] = (f16)0; blo[i] = (f16)0; }
    if (g == 0) {
        f16 h;
        h=(f16)fx0; bh[0]=h; blo[0]=(f16)(fx0-(float)h);
        h=(f16)fx1; bh[1]=h; blo[1]=(f16)(fx1-(float)h);
        h=(f16)fx2; bh[2]=h; blo[2]=(f16)(fx2-(float)h);
        h=(f16)fx3; bh[3]=h; blo[3]=(f16)(fx3-(float)h);
        h=(f16)fx4; bh[4]=h; blo[4]=(f16)(fx4-(float)h);
        h=(f16)fx5; bh[5]=h; blo[5]=(f16)(fx5-(float)h);
        h=(f16)fx6; bh[6]=h; blo[6]=(f16)(fx6-(float)h);
        h=(f16)fx7; bh[7]=h; blo[7]=(f16)(fx7-(float)h);
    } else {
        f16 h = (f16)ay; bh[0] = h; blo[0] = (f16)(ay - (float)h);
    }

    // ---- MLP fully in registers; weights streamed from LDS ----
    f16x8 Pa0,Pa1,Pa2,Pa3,Pa4,Pa5,Pa6,Pa7;
    f16x8 Pb0,Pb1,Pb2,Pb3,Pb4,Pb5,Pb6,Pb7;

    L0FB(0, Pa0, Pa1);  L0FB(1, Pa2, Pa3);  L0FB(2, Pa4, Pa5);  L0FB(3, Pa6, Pa7);

    MIDLAYER(LW0, 1, Pa0,Pa1,Pa2,Pa3,Pa4,Pa5,Pa6,Pa7, Pb0,Pb1,Pb2,Pb3,Pb4,Pb5,Pb6,Pb7)
    MIDLAYER(LW1, 2, Pb0,Pb1,Pb2,Pb3,Pb4,Pb5,Pb6,Pb7, Pa0,Pa1,Pa2,Pa3,Pa4,Pa5,Pa6,Pa7)
    MIDLAYER(LW2, 3, Pa0,Pa1,Pa2,Pa3,Pa4,Pa5,Pa6,Pa7, Pb0,Pb1,Pb2,Pb3,Pb4,Pb5,Pb6,Pb7)

    // ---- final layer 128 -> 2 (rows 0,1 of D), atomic segment-sum ----
    {
        f32x16 acc;
        #pragma unroll
        for (int r = 0; r < 16; ++r) acc[r] = 0.0f;
        if (g == 0) { acc[0] = b4[0]; acc[1] = b4[1]; }
        const f16* wb = lds + W4F + lane * 8;
        f16x8 w;
        w = *(const f16x8*)(wb + 0*512); acc = MF(w, Pb0, acc);
        w = *(const f16x8*)(wb + 1*512); acc = MF(w, Pb1, acc);
        w = *(const f16x8*)(wb + 2*512); acc = MF(w, Pb2, acc);
        w = *(const f16x8*)(wb + 3*512); acc = MF(w, Pb3, acc);
        w = *(const f16x8*)(wb + 4*512); acc = MF(w, Pb4, acc);
        w = *(const f16x8*)(wb + 5*512); acc = MF(w, Pb5, acc);
        w = *(const f16x8*)(wb + 6*512); acc = MF(w, Pb6, acc);
        w = *(const f16x8*)(wb + 7*512); acc = MF(w, Pb7, acc);
        if (g == 0) {
            atomicAdd(&out[2 * dsti],     acc[0]);
            atomicAdd(&out[2 * dsti + 1], acc[1]);
        }
    }
}

extern "C" void kernel_launch(void* const* d_in, const int* in_sizes, int n_in,
                              void* d_out, int out_size, void* d_ws, size_t ws_size,
                              hipStream_t stream) {
    const float* pos   = (const float*)d_in[0];
    const float* vel   = (const float*)d_in[1];
    const float* a     = (const float*)d_in[2];
    const float* vnorm = (const float*)d_in[3];
    const float* w0    = (const float*)d_in[4];
    const float* b0    = (const float*)d_in[5];
    const float* w1    = (const float*)d_in[6];
    const float* b1    = (const float*)d_in[7];
    const float* w2    = (const float*)d_in[8];
    const float* b2    = (const float*)d_in[9];
    const float* w3    = (const float*)d_in[10];
    const float* b3    = (const float*)d_in[11];
    const float* w4    = (const float*)d_in[12];
    const float* b4    = (const float*)d_in[13];
    const int*   ei    = (const int*)d_in[14];
    const int*   did   = (const int*)d_in[15];
    float* out = (float*)d_out;
    f16* ws = (f16*)d_ws;

    int nEdges = in_sizes[14] / 2;   // 800000
    int nNodes = in_sizes[0] / 2;    // 50000

    hipFuncSetAttribute((const void*)gnn_mfma,
                        hipFuncAttributeMaxDynamicSharedMemorySize, WS_F16 * 2);

    hipLaunchKernelGGL(zero_f32, dim3((out_size + 255) / 256), dim3(256), 0, stream,
                       out, out_size);
    hipLaunchKernelGGL(prep_weights, dim3(227), dim3(256), 0, stream,
                       w1, w2, w3, w0, b0, b1, b2, b3, w4, ws);
    int nChunks = nEdges / 32;                    // 25000
    int grid = (nChunks + 15) / 16;               // 1563 blocks of 16 waves
    hipLaunchKernelGGL(gnn_mfma, dim3(grid), dim3(1024), WS_F16 * 2, stream,
                       pos, vel, a, vnorm, b4, ei, did, ws, out,
                       nNodes, nEdges);
}